// Round 13
// baseline (525.160 us; speedup 1.0000x reference)
//
#include <hip/hip_runtime.h>
#include <stdint.h>

typedef float v4f  __attribute__((ext_vector_type(4)));
typedef float v16f __attribute__((ext_vector_type(16)));
typedef int   v4i  __attribute__((ext_vector_type(4)));

__device__ __forceinline__ void gload_lds16(const void* g, void* l) {
  __builtin_amdgcn_global_load_lds(
      (const __attribute__((address_space(1))) void*)g,
      (__attribute__((address_space(3))) void*)l, 16, 0, 0);
}
__device__ __forceinline__ void gload_lds4(const void* g, void* l) {
  __builtin_amdgcn_global_load_lds(
      (const __attribute__((address_space(1))) void*)g,
      (__attribute__((address_space(3))) void*)l, 4, 0, 0);
}

// ---------------------------------------------------------------------------
// Fused FWHT + MXFP4 quantize, x and w in ONE launch (r11, proven).
// Layouts: packed k-major (kb*R+row)*16; scales dword (kt*2+hik)*R+row, byte ks.
// ---------------------------------------------------------------------------
__global__ __launch_bounds__(256) void quant_fp4_all(
    const float* __restrict__ x, const float* __restrict__ w,
    uint32_t* __restrict__ xpk, uint32_t* __restrict__ wpk,
    uint8_t* __restrict__ xsc, uint8_t* __restrict__ wsc) {
  int bid = blockIdx.x;
  const float* in; uint32_t* packed; uint8_t* scales; int R, rblkbits;
  if (bid < 4096) { in = x; packed = xpk; scales = xsc; R = 8192;  rblkbits = 10; }
  else { bid -= 4096; in = w; packed = wpk; scales = wsc; R = 16384; rblkbits = 11; }

  const int tid = threadIdx.x;
  const int row = ((bid & ((1 << rblkbits) - 1)) << 3) + (tid & 7);
  const int kb  = ((bid >> rblkbits) << 5) + (tid >> 3);

  float v[32];
  const v4f* p = (const v4f*)(in + (size_t)row * 4096 + kb * 32);
#pragma unroll
  for (int c = 0; c < 8; ++c) {
    v4f t = p[c];
    v[c * 4 + 0] = t[0]; v[c * 4 + 1] = t[1];
    v[c * 4 + 2] = t[2]; v[c * 4 + 3] = t[3];
  }
#pragma unroll
  for (int s = 0; s < 5; ++s) {
    const int h = 1 << s;
#pragma unroll
    for (int k = 0; k < 16; ++k) {
      const int i = ((k >> s) << (s + 1)) | (k & (h - 1));
      float a = v[i], b = v[i + h];
      v[i] = a + b; v[i + h] = a - b;
    }
  }
  const float RS = 0.17677669529663687f;  // 32^-0.5
  float amax = 0.0f;
#pragma unroll
  for (int i = 0; i < 32; ++i) {
    v[i] *= RS;
    amax = fmaxf(amax, fabsf(v[i]));
  }
  int E;
  float rscale;
  if (amax > 0.0f) {
    float am = fmaxf(amax, 1e-30f);
    E = (int)((__float_as_uint(am) >> 23) & 255u) - 127;
    rscale = __uint_as_float((uint32_t)(2 - E + 127) << 23);
  } else { E = 2; rscale = 1.0f; }

  uint32_t dw[4] = {0u, 0u, 0u, 0u};
#pragma unroll
  for (int i = 0; i < 32; ++i) {
    float xx = v[i];
    float a = fminf(fabsf(xx) * rscale, 6.0f);
    float rstep = a >= 4.0f ? 0.5f : (a >= 2.0f ? 1.0f : 2.0f);
    float step  = a >= 4.0f ? 2.0f : (a >= 2.0f ? 1.0f : 0.5f);
    float q = rintf(a * rstep) * step;          // RNE onto e2m1 grid
    uint32_t uq = __float_as_uint(q);
    int Eq = (int)(uq >> 23) - 127;
    uint32_t code = (q == 0.0f) ? 0u
                  : (Eq < 0 ? 1u
                            : (((uint32_t)(Eq + 1) << 1) | ((uq >> 22) & 1u)));
    code |= (__float_as_uint(xx) >> 31) << 3;
    dw[i >> 3] |= code << (4 * (i & 7));
  }
  uint4 o; o.x = dw[0]; o.y = dw[1]; o.z = dw[2]; o.w = dw[3];
  *(uint4*)(packed + ((size_t)kb * R + row) * 4) = o;

  const int kt = kb >> 3, hik = kb & 1, ks = (kb >> 1) & 3;
  scales[(size_t)((kt * 2 + hik) * R + row) * 4 + ks] = (uint8_t)(E - 2 + 127);
}

// ---------------------------------------------------------------------------
// MXFP4 GEMM, B^T: 128x128 tile, BK=256, 4 waves (2Mx2N, wave-tile 64x64,
// acc=64 AGPR), dbuf 68KB LDS => 2 INDEPENDENT blocks/CU (m114 overlap).
// 1-phase/tile: STG(t+1)->other buf first, compute, VMW(0)+barrier.
// FIX vs round 12: region bases (+16384 for B) live ONLY at the use site —
// bRd no longer pre-adds it (round-8 bug class, recurred).
// ---------------------------------------------------------------------------
#define MFMA4(a, b, c, sa, sb) \
  __builtin_amdgcn_mfma_scale_f32_32x32x64_f8f6f4((a), (b), (c), 4, 4, 0, (sa), 0, (sb))
#define PAD8(x) __builtin_shufflevector((x), (x), 0, 1, 2, 3, -1, -1, -1, -1)
#define BARRIER { asm volatile("" ::: "memory"); __builtin_amdgcn_s_barrier(); asm volatile("" ::: "memory"); }
#define SB0 __builtin_amdgcn_sched_barrier(0)
#define VMW(n)  asm volatile("s_waitcnt vmcnt(" #n ")" ::: "memory")

#define BUF_SZ 34816   // A 16KB @0, B 16KB @16384, Asc 1KB @32768, Bsc 1KB @33792

__global__ __launch_bounds__(256, 2) void gemm_fp4_128(
    const uint8_t* __restrict__ Apk, const uint8_t* __restrict__ Bpk,
    const uint32_t* __restrict__ Asc, const uint32_t* __restrict__ Bsc,
    const float* __restrict__ bias, float* __restrict__ C) {
  const int N = 16384;
  __shared__ uint8_t lds[2 * BUF_SZ];

  const int tid = threadIdx.x, lane = tid & 63, wv = tid >> 6;  // 4 waves
  const int wm = wv >> 1, wn = wv & 1;
  const int hi = lane >> 5, r32 = lane & 31;

  // XCD clustering: 8192 blocks = 8 xcd x 16 supertiles x 64 blocks(8m x 8n)
  const int bid = blockIdx.x;
  const int xcd = bid & 7, idx = bid >> 3;
  const int st = idx >> 6, loc = idx & 63;
  const int mT = ((st & 7) * 8 + (loc & 7)) * 128;
  const int nT = (xcd * 16 + (st >> 3) * 8 + (loc >> 3)) * 128;

  // ---- staging maps: per thread 4 A-chunks, 4 B-chunks, 2 scale dwords
  size_t aOff[4], bOff[4]; int dOff[4];
#pragma unroll
  for (int q = 0; q < 4; ++q) {
    const int c = q * 256 + tid;              // 1024 chunks: kc=c>>7, row=c&127
    aOff[q] = ((size_t)(c >> 7) * 8192  + mT + (c & 127)) * 16;
    bOff[q] = ((size_t)(c >> 7) * 16384 + nT + (c & 127)) * 16;
    dOff[q] = c * 16;
  }
  const int scQ = tid >> 7, scR = tid & 127;  // hik = scQ, row offset scR
  const int scDst = scQ * 512 + scR * 4;

  auto STG = [&](int t, int b) {
    const uint8_t* ga = Apk + (size_t)t * 1048576;   // 8 kb * 8192 rows * 16B
    const uint8_t* gb = Bpk + (size_t)t * 2097152;
    uint8_t* la = &lds[b * BUF_SZ];
#pragma unroll
    for (int q = 0; q < 4; ++q) gload_lds16(ga + aOff[q], la + dOff[q]);
#pragma unroll
    for (int q = 0; q < 4; ++q) gload_lds16(gb + bOff[q], la + 16384 + dOff[q]);
    gload_lds4(Asc + (size_t)(2 * t + scQ) * 8192  + mT + scR, la + 32768 + scDst);
    gload_lds4(Bsc + (size_t)(2 * t + scQ) * 16384 + nT + scR, la + 33792 + scDst);
  };

  // ---- compute-side addressing (NO region bases here — added at use site)
  const int aRd  = (wm * 64 + r32) * 16;     // use: b*BUF_SZ + (2j+hi)*2048 + aRd + mf*512
  const int bRd  = (wn * 64 + r32) * 16;     // use: b*BUF_SZ + 16384 + (2j+hi)*2048 + bRd + nf*512
  const int aScO = hi * 512 + (wm * 64 + r32) * 4;   // use: b*BUF_SZ + 32768 + aScO + mf*128
  const int bScO = hi * 512 + (wn * 64 + r32) * 4;   // use: b*BUF_SZ + 33792 + bScO + nf*128

  v16f acc[2][2] = {};

  // ---- prologue
  STG(0, 0);
  VMW(0);
  BARRIER;

  // ---- main: 16 K-tiles, dbuf, distance-1 prefetch issued FIRST
#pragma unroll 1
  for (int t = 0; t < 16; ++t) {
    const int b = t & 1;
    if (t < 15) STG(t + 1, b ^ 1);
    SB0;   // staging issues before compute's ds_reads

    uint32_t saD[2], sbD[2];
#pragma unroll
    for (int mf = 0; mf < 2; ++mf)
      saD[mf] = *(const uint32_t*)&lds[b * BUF_SZ + 32768 + aScO + mf * 128];
#pragma unroll
    for (int nf = 0; nf < 2; ++nf)
      sbD[nf] = *(const uint32_t*)&lds[b * BUF_SZ + 33792 + bScO + nf * 128];

#pragma unroll
    for (int j = 0; j < 4; ++j) {
      v4i fa[2], fb[2];
#pragma unroll
      for (int mf = 0; mf < 2; ++mf)
        fa[mf] = *(const v4i*)&lds[b * BUF_SZ + (2 * j + hi) * 2048 + aRd + mf * 512];
#pragma unroll
      for (int nf = 0; nf < 2; ++nf)
        fb[nf] = *(const v4i*)&lds[b * BUF_SZ + 16384 + (2 * j + hi) * 2048 + bRd + nf * 512];
      __builtin_amdgcn_s_setprio(1);
#pragma unroll
      for (int mf = 0; mf < 2; ++mf)
#pragma unroll
        for (int nf = 0; nf < 2; ++nf)
          acc[mf][nf] = MFMA4(PAD8(fa[mf]), PAD8(fb[nf]), acc[mf][nf],
                              (int)((saD[mf] >> (8 * j)) & 255u),
                              (int)((sbD[nf] >> (8 * j)) & 255u));
      __builtin_amdgcn_s_setprio(0);
    }

    if (t < 15) { VMW(0); BARRIER; }   // tile t+1 resident; frees buf b
  }

  // ---- epilogue: 32x32 C/D layout col=lane&31, row=(q&3)+8*(q>>2)+4*hi
#pragma unroll
  for (int nf = 0; nf < 2; ++nf) {
    const int col = nT + wn * 64 + nf * 32 + r32;
    const float bv = bias[col];
#pragma unroll
    for (int mf = 0; mf < 2; ++mf) {
      const int rbase = mT + wm * 64 + mf * 32 + 4 * hi;
#pragma unroll
      for (int q = 0; q < 16; ++q) {
        const int rowl = (q & 3) + 8 * (q >> 2);
        C[(size_t)(rbase + rowl) * N + col] = acc[mf][nf][q] + bv;
      }
    }
  }
}

// ---------------------------------------------------------------------------
extern "C" void kernel_launch(void* const* d_in, const int* in_sizes, int n_in,
                              void* d_out, int out_size, void* d_ws, size_t ws_size,
                              hipStream_t stream) {
  const float* x    = (const float*)d_in[0];   // 8192 x 4096
  const float* w    = (const float*)d_in[1];   // 16384 x 4096
  const float* bias = (const float*)d_in[2];   // 16384
  float* out = (float*)d_out;                  // 8192 x 16384 fp32

  uint8_t* x_pk = (uint8_t*)d_ws;                        // 16 MB
  uint8_t* w_pk = x_pk + (size_t)16 * 1024 * 1024;       // 32 MB
  uint8_t* x_sc = w_pk + (size_t)32 * 1024 * 1024;       // 1 MB
  uint8_t* w_sc = x_sc + (size_t)1  * 1024 * 1024;       // 2 MB

  quant_fp4_all<<<12288, 256, 0, stream>>>(
      x, w, (uint32_t*)x_pk, (uint32_t*)w_pk, x_sc, w_sc);

  gemm_fp4_128<<<8192, dim3(256), 0, stream>>>(
      x_pk, w_pk, (const uint32_t*)x_sc, (const uint32_t*)w_sc, bias, out);
}

// Round 14
// 448.358 us; speedup vs baseline: 1.1713x; 1.1713x over previous
//
#include <hip/hip_runtime.h>
#include <stdint.h>

typedef float v4f  __attribute__((ext_vector_type(4)));
typedef float v16f __attribute__((ext_vector_type(16)));
typedef int   v4i  __attribute__((ext_vector_type(4)));

__device__ __forceinline__ void gload_lds16(const void* g, void* l) {
  __builtin_amdgcn_global_load_lds(
      (const __attribute__((address_space(1))) void*)g,
      (__attribute__((address_space(3))) void*)l, 16, 0, 0);
}
__device__ __forceinline__ void gload_lds4(const void* g, void* l) {
  __builtin_amdgcn_global_load_lds(
      (const __attribute__((address_space(1))) void*)g,
      (__attribute__((address_space(3))) void*)l, 4, 0, 0);
}

// ---------------------------------------------------------------------------
// Fused FWHT + MXFP4 quantize, x and w in ONE launch (round-11, measured
// ~92us, proven byte-compatible). Layouts: packed k-major (kb*R+row)*16;
// scales dword (kt*2+hik)*R+row, byte ks (kt=kb>>3, hik=kb&1, ks=(kb>>1)&3).
// ---------------------------------------------------------------------------
__global__ __launch_bounds__(256) void quant_fp4_all(
    const float* __restrict__ x, const float* __restrict__ w,
    uint32_t* __restrict__ xpk, uint32_t* __restrict__ wpk,
    uint8_t* __restrict__ xsc, uint8_t* __restrict__ wsc) {
  int bid = blockIdx.x;
  const float* in; uint32_t* packed; uint8_t* scales; int R, rblkbits;
  if (bid < 4096) { in = x; packed = xpk; scales = xsc; R = 8192;  rblkbits = 10; }
  else { bid -= 4096; in = w; packed = wpk; scales = wsc; R = 16384; rblkbits = 11; }

  const int tid = threadIdx.x;
  const int row = ((bid & ((1 << rblkbits) - 1)) << 3) + (tid & 7);
  const int kb  = ((bid >> rblkbits) << 5) + (tid >> 3);

  float v[32];
  const v4f* p = (const v4f*)(in + (size_t)row * 4096 + kb * 32);
#pragma unroll
  for (int c = 0; c < 8; ++c) {
    v4f t = p[c];
    v[c * 4 + 0] = t[0]; v[c * 4 + 1] = t[1];
    v[c * 4 + 2] = t[2]; v[c * 4 + 3] = t[3];
  }
#pragma unroll
  for (int s = 0; s < 5; ++s) {
    const int h = 1 << s;
#pragma unroll
    for (int k = 0; k < 16; ++k) {
      const int i = ((k >> s) << (s + 1)) | (k & (h - 1));
      float a = v[i], b = v[i + h];
      v[i] = a + b; v[i + h] = a - b;
    }
  }
  const float RS = 0.17677669529663687f;  // 32^-0.5
  float amax = 0.0f;
#pragma unroll
  for (int i = 0; i < 32; ++i) {
    v[i] *= RS;
    amax = fmaxf(amax, fabsf(v[i]));
  }
  int E;
  float rscale;
  if (amax > 0.0f) {
    float am = fmaxf(amax, 1e-30f);
    E = (int)((__float_as_uint(am) >> 23) & 255u) - 127;
    rscale = __uint_as_float((uint32_t)(2 - E + 127) << 23);
  } else { E = 2; rscale = 1.0f; }

  uint32_t dw[4] = {0u, 0u, 0u, 0u};
#pragma unroll
  for (int i = 0; i < 32; ++i) {
    float xx = v[i];
    float a = fminf(fabsf(xx) * rscale, 6.0f);
    float rstep = a >= 4.0f ? 0.5f : (a >= 2.0f ? 1.0f : 2.0f);
    float step  = a >= 4.0f ? 2.0f : (a >= 2.0f ? 1.0f : 0.5f);
    float q = rintf(a * rstep) * step;          // RNE onto e2m1 grid
    uint32_t uq = __float_as_uint(q);
    int Eq = (int)(uq >> 23) - 127;
    uint32_t code = (q == 0.0f) ? 0u
                  : (Eq < 0 ? 1u
                            : (((uint32_t)(Eq + 1) << 1) | ((uq >> 22) & 1u)));
    code |= (__float_as_uint(xx) >> 31) << 3;
    dw[i >> 3] |= code << (4 * (i & 7));
  }
  uint4 o; o.x = dw[0]; o.y = dw[1]; o.z = dw[2]; o.w = dw[3];
  *(uint4*)(packed + ((size_t)kb * R + row) * 4) = o;

  const int kt = kb >> 3, hik = kb & 1, ks = (kb >> 1) & 3;
  scales[(size_t)((kt * 2 + hik) * R + row) * 4 + ks] = (uint8_t)(E - 2 + 127);
}

// ---------------------------------------------------------------------------
// MXFP4 GEMM, B^T, 256x256 tile, BK=256, 8 waves (2Mx4N) — ROUND-10 KERNEL
// VERBATIM (measured 340us, MfmaUtil 37%, FETCH 213MB, conflicts 0).
// 2 phases/K-tile, counted vmcnt VMW(6)/tile, scales staged via LDS.
// ---------------------------------------------------------------------------
#define MFMA4(a, b, c, sa, sb) \
  __builtin_amdgcn_mfma_scale_f32_32x32x64_f8f6f4((a), (b), (c), 4, 4, 0, (sa), 0, (sb))
#define PAD8(x) __builtin_shufflevector((x), (x), 0, 1, 2, 3, -1, -1, -1, -1)
#define BARRIER { asm volatile("" ::: "memory"); __builtin_amdgcn_s_barrier(); asm volatile("" ::: "memory"); }
#define SB0 __builtin_amdgcn_sched_barrier(0)
#define LGKM0 { asm volatile("s_waitcnt lgkmcnt(0)" ::: "memory"); SB0; }
#define VMW(n)  asm volatile("s_waitcnt vmcnt(" #n ")" ::: "memory")

__global__ __launch_bounds__(512, 2) void gemm_fp4_2x(
    const uint8_t* __restrict__ Apk, const uint8_t* __restrict__ Bpk,
    const uint32_t* __restrict__ Asc, const uint32_t* __restrict__ Bsc,
    const float* __restrict__ bias, float* __restrict__ C) {
  const int N = 16384;
  __shared__ uint8_t lds[139264];

  const int tid = threadIdx.x, lane = tid & 63, wv = tid >> 6;
  const int wm = wv >> 2, wn = wv & 3;           // 2M x 4N waves
  const int hi = lane >> 5, r32 = lane & 31;

  // XCD-aware bijective swizzle (2048 blocks, 8m x 4n clusters per XCD)
  const int bid = blockIdx.x;
  const int xcd = bid & 7, idx = bid >> 3, st = idx >> 5;
  const int mT = ((st & 3) * 8 + (idx & 7)) * 256;
  const int nT = (xcd * 8 + (st >> 2) * 4 + ((idx >> 3) & 3)) * 256;

  // ---- operand staging map
  const int sOp = wv >> 2;                 // 0:A 1:B
  const int sR2 = (wv >> 1) & 1;           // kc LSB
  const int s0  = 2 * (wv & 1);            // row-block base
  const uint8_t* opBase = sOp ? Bpk : Apk;
  const size_t RB = sOp ? (size_t)16384 * 16 : (size_t)8192 * 16;  // bytes/kb
  const int T0 = sOp ? nT : mT;
  const size_t gOff0 = (size_t)(T0 + (s0 + 0) * 64 + lane) * 16;
  const size_t gOff1 = (size_t)(T0 + (s0 + 1) * 64 + lane) * 16;
  const int dOff0 = sOp * 32768 + sR2 * 4096 + (s0 + 0) * 1024 + lane * 16;
  const int dOff1 = sOp * 32768 + sR2 * 4096 + (s0 + 1) * 1024 + lane * 16;

  auto STG_OPS = [&](int kt, int a, int bb) {
    const uint8_t* g0 = opBase + (size_t)(kt * 8 + a + sR2) * RB;
    uint8_t* l = &lds[bb * 65536 + a * 4096];
    gload_lds16(g0 + gOff0, l + dOff0);
    gload_lds16(g0 + gOff1, l + dOff1);
  };

  const uint32_t* scBase = sOp ? Bsc : Asc;
  const int Rrows = sOp ? 16384 : 8192;
  auto STG_SC = [&](int kt, int bb) {
    const uint32_t* g = scBase + (size_t)(kt * 2 + sR2) * Rrows + T0;
    uint8_t* l = &lds[131072 + bb * 4096 + sOp * 2048 + sR2 * 1024];
    gload_lds4(g + (s0 + 0) * 64 + lane, l + (s0 + 0) * 256 + lane * 4);
    gload_lds4(g + (s0 + 1) * 64 + lane, l + (s0 + 1) * 256 + lane * 4);
  };

  // ---- compute-side bases
  const int aRd0 = hi * 4096 + (wm * 128 + r32) * 16;
  const int aRd1 = aRd0 + 65536;
  const int bRd0 = 32768 + hi * 4096 + (wn * 64 + r32) * 16;
  const int bRd1 = bRd0 + 65536;
  const int aSc0 = 131072 + hi * 1024 + (wm * 128 + r32) * 4;
  const int aSc1 = aSc0 + 4096;
  const int bSc0 = 131072 + 2048 + hi * 1024 + (wn * 64 + r32) * 4;
  const int bSc1 = bSc0 + 4096;

  v16f acc[4][2] = {};
  v4i fA0[4], fB0[2], fA1[4], fB1[2];
  uint32_t saD[4], sbD[2];

#define LDF(FA, FB, ARD, BRD, j) { \
    _Pragma("unroll") for (int mf = 0; mf < 4; ++mf) \
      FA[mf] = *(const v4i*)&lds[(ARD) + (j) * 8192 + mf * 512]; \
    _Pragma("unroll") for (int nf = 0; nf < 2; ++nf) \
      FB[nf] = *(const v4i*)&lds[(BRD) + (j) * 8192 + nf * 512]; }

#define SCRD(ASC, BSC) { \
    _Pragma("unroll") for (int mf = 0; mf < 4; ++mf) \
      saD[mf] = *(const uint32_t*)&lds[(ASC) + mf * 128]; \
    _Pragma("unroll") for (int nf = 0; nf < 2; ++nf) \
      sbD[nf] = *(const uint32_t*)&lds[(BSC) + nf * 128]; }

#define MM8(FA, FB, j) { \
    __builtin_amdgcn_s_setprio(1); \
    _Pragma("unroll") for (int mf = 0; mf < 4; ++mf) \
    _Pragma("unroll") for (int nf = 0; nf < 2; ++nf) \
      acc[mf][nf] = MFMA4(PAD8(FA[mf]), PAD8(FB[nf]), acc[mf][nf], \
                          (int)((saD[mf] >> (8 * (j))) & 255u), \
                          (int)((sbD[nf] >> (8 * (j))) & 255u)); \
    __builtin_amdgcn_s_setprio(0); }

  // 2-phase tile: ph0 reads kc0-3 (j0,j1), ph1 reads kc4-7 (j2,j3).
#define TILE2(bb, t, ARD, BRD, ASC, BSC, ob) { \
    /* ph0 */ \
    SCRD(ASC, BSC); \
    LDF(fA0, fB0, ARD, BRD, 0); SB0; LDF(fA1, fB1, ARD, BRD, 1); \
    STG_OPS((t) + 1, 4, ob); STG_OPS((t) + 1, 6, ob); SB0; \
    BARRIER; LGKM0; \
    MM8(fA0, fB0, 0); MM8(fA1, fB1, 1); \
    BARRIER; \
    /* ph1 */ \
    LDF(fA0, fB0, ARD, BRD, 2); SB0; LDF(fA1, fB1, ARD, BRD, 3); \
    STG_OPS((t) + 2, 0, bb); STG_OPS((t) + 2, 2, bb); STG_SC((t) + 2, bb); SB0; \
    BARRIER; LGKM0; \
    MM8(fA0, fB0, 2); MM8(fA1, fB1, 3); \
    VMW(6); BARRIER; }

  // ---- prologue: tile0 full (10 ops) -> buf0; tile1 kc0,kc2+SC (6) -> buf1
  STG_OPS(0, 0, 0); STG_OPS(0, 2, 0); STG_OPS(0, 4, 0); STG_OPS(0, 6, 0);
  STG_SC(0, 0);
  STG_OPS(1, 0, 1); STG_OPS(1, 2, 1);
  STG_SC(1, 1);
  VMW(6);   // tile0 resident; tile1's 6 ops in flight
  BARRIER;

  // ---- main: tiles 0..13
#pragma unroll 1
  for (int i = 0; i < 7; ++i) {
    const int t0 = 2 * i;
    TILE2(0, t0,     aRd0, bRd0, aSc0, bSc0, 1);
    TILE2(1, t0 + 1, aRd1, bRd1, aSc1, bSc1, 0);
  }

  // ---- tail tile 14 (buf0): ph0 completes tile 15 (kc4,kc6 -> buf1)
  SCRD(aSc0, bSc0);
  LDF(fA0, fB0, aRd0, bRd0, 0); SB0; LDF(fA1, fB1, aRd0, bRd0, 1);
  STG_OPS(15, 4, 1); STG_OPS(15, 6, 1); SB0;
  BARRIER; LGKM0;
  MM8(fA0, fB0, 0); MM8(fA1, fB1, 1);
  BARRIER;
  LDF(fA0, fB0, aRd0, bRd0, 2); SB0; LDF(fA1, fB1, aRd0, bRd0, 3);
  BARRIER; LGKM0;
  MM8(fA0, fB0, 2); MM8(fA1, fB1, 3);
  VMW(0); BARRIER;

  // ---- tail tile 15 (buf1): no staging, no vm waits
  SCRD(aSc1, bSc1);
  LDF(fA0, fB0, aRd1, bRd1, 0); SB0; LDF(fA1, fB1, aRd1, bRd1, 1);
  LGKM0;
  MM8(fA0, fB0, 0); MM8(fA1, fB1, 1);
  LDF(fA0, fB0, aRd1, bRd1, 2); SB0; LDF(fA1, fB1, aRd1, bRd1, 3);
  LGKM0;
  MM8(fA0, fB0, 2); MM8(fA1, fB1, 3);

  // ---- epilogue: 32x32 C/D layout col=lane&31, row=(q&3)+8*(q>>2)+4*hi
#pragma unroll
  for (int nf = 0; nf < 2; ++nf) {
    const int col = nT + wn * 64 + nf * 32 + r32;
    const float bv = bias[col];
#pragma unroll
    for (int mf = 0; mf < 4; ++mf) {
      const int rbase = mT + wm * 128 + mf * 32 + 4 * hi;
#pragma unroll
      for (int q = 0; q < 16; ++q) {
        const int rowl = (q & 3) + 8 * (q >> 2);
        C[(size_t)(rbase + rowl) * N + col] = acc[mf][nf][q] + bv;
      }
    }
  }
}

// ---------------------------------------------------------------------------
extern "C" void kernel_launch(void* const* d_in, const int* in_sizes, int n_in,
                              void* d_out, int out_size, void* d_ws, size_t ws_size,
                              hipStream_t stream) {
  const float* x    = (const float*)d_in[0];   // 8192 x 4096
  const float* w    = (const float*)d_in[1];   // 16384 x 4096
  const float* bias = (const float*)d_in[2];   // 16384
  float* out = (float*)d_out;                  // 8192 x 16384 fp32

  uint8_t* x_pk = (uint8_t*)d_ws;                        // 16 MB
  uint8_t* w_pk = x_pk + (size_t)16 * 1024 * 1024;       // 32 MB
  uint8_t* x_sc = w_pk + (size_t)32 * 1024 * 1024;       // 1 MB
  uint8_t* w_sc = x_sc + (size_t)1  * 1024 * 1024;       // 2 MB

  quant_fp4_all<<<12288, 256, 0, stream>>>(
      x, w, (uint32_t*)x_pk, (uint32_t*)w_pk, x_sc, w_sc);

  gemm_fp4_2x<<<2048, dim3(512), 0, stream>>>(
      x_pk, w_pk, (const uint32_t*)x_sc, (const uint32_t*)w_sc, bias, out);
}